// Round 1
// baseline (655.850 us; speedup 1.0000x reference)
//
#include <hip/hip_runtime.h>
#include <hip/hip_bf16.h>

// ---------------------------------------------------------------------------
// GAT 2-layer model on MI355X.
// Layer1: h = x@W1 [8192,6144], 8-head attention, +b1, ELU -> h2 (bf16)
// Layer2: y = h2@W2 [8192,768], 1-head attention, +b2 -> out (fp32)
// GEMMs in bf16 MFMA (16x16x32), attention via atomics + CSR aggregation.
// ---------------------------------------------------------------------------

#define N_NODES 8192
#define N_EDGES 32768
#define E_TOT   (N_EDGES + N_NODES)   // self-loops appended
#define D_IN    768
#define H1      8
#define HC1     (H1 * D_IN)           // 6144

typedef unsigned short ushort_t;
using short8  = __attribute__((ext_vector_type(8))) short;
using floatx4 = __attribute__((ext_vector_type(4))) float;

__device__ __forceinline__ float bf2f(unsigned short u) {
  return __uint_as_float(((unsigned)u) << 16);
}
__device__ __forceinline__ unsigned short f2bf(float f) {
  unsigned u = __float_as_uint(f);
  unsigned r = (u + 0x7fffu + ((u >> 16) & 1u)) >> 16;  // RNE
  return (unsigned short)r;
}
// order-preserving float<->uint for atomicMax on floats (incl. negatives)
__device__ __forceinline__ unsigned fenc(float f) {
  unsigned u = __float_as_uint(f);
  return (u & 0x80000000u) ? ~u : (u | 0x80000000u);
}
__device__ __forceinline__ float fdec(unsigned u) {
  return __uint_as_float((u & 0x80000000u) ? (u ^ 0x80000000u) : ~u);
}

__device__ __forceinline__ void async_copy16(void* lds, const void* g) {
  __builtin_amdgcn_global_load_lds(
      (__attribute__((address_space(1))) void*)(g),
      (__attribute__((address_space(3))) void*)(lds), 16, 0, 0);
}

// ---------------------------------------------------------------------------
// elementwise fp32 -> bf16 (vectorized float4 -> 4x bf16)
// ---------------------------------------------------------------------------
__global__ void convert_bf16_kernel(const float* __restrict__ in,
                                    ushort_t* __restrict__ out, int n4) {
  int i = blockIdx.x * blockDim.x + threadIdx.x;
  if (i >= n4) return;
  float4 v = ((const float4*)in)[i];
  ushort_t r[4] = {f2bf(v.x), f2bf(v.y), f2bf(v.z), f2bf(v.w)};
  *((ushort4*)(out + (size_t)i * 4)) = *(ushort4*)r;
}

// ---------------------------------------------------------------------------
// fp32 [R][C] -> bf16 transpose [C][R]
// ---------------------------------------------------------------------------
__global__ void transpose_f2b_kernel(const float* __restrict__ in,
                                     ushort_t* __restrict__ out, int R, int C) {
  __shared__ float tile[32][33];
  int bx = blockIdx.x * 32;  // col base (output row base)
  int by = blockIdx.y * 32;  // row base
  int tx = threadIdx.x, ty = threadIdx.y;  // (32, 8)
#pragma unroll
  for (int i = 0; i < 32; i += 8)
    tile[ty + i][tx] = in[(size_t)(by + ty + i) * C + bx + tx];
  __syncthreads();
#pragma unroll
  for (int i = 0; i < 32; i += 8)
    out[(size_t)(bx + ty + i) * R + by + tx] = f2bf(tile[tx][ty + i]);
}

// ---------------------------------------------------------------------------
// bf16 GEMM: C[M][N] = A[M][K] * Bt[N][K]^T.  128x128 tile, BK=32.
// LDS in MFMA-fragment order: slot = (16row-block)*64 + (kquad*16 + row%16),
// so ds_read_b128 per fragment is a contiguous 1KB wave read.
// ---------------------------------------------------------------------------
__global__ __launch_bounds__(256) void gemm_bf16_kernel(
    const ushort_t* __restrict__ A, const ushort_t* __restrict__ Bt,
    ushort_t* __restrict__ C, int M, int N, int K) {
  __shared__ short8 Ash[512];  // 8 KB: 8 blocks x 64 slots
  __shared__ short8 Bsh[512];
  const int tid = threadIdx.x;
  const int lane = tid & 63;
  const int w = tid >> 6;
  const int wm = w >> 1, wn = w & 1;
  const int m0 = blockIdx.y * 128;
  const int n0 = blockIdx.x * 128;
  const int lrow = lane & 15;
  const int lq = lane >> 4;

  floatx4 acc[4][4];
#pragma unroll
  for (int i = 0; i < 4; ++i)
#pragma unroll
    for (int j = 0; j < 4; ++j) acc[i][j] = {0.f, 0.f, 0.f, 0.f};

  for (int k0 = 0; k0 < K; k0 += 32) {
    __syncthreads();  // previous iter LDS reads done
#pragma unroll
    for (int ii = 0; ii < 2; ++ii) {
      int blk = 2 * w + ii;  // 16-row block of the tile
      const ushort_t* sa = A + (size_t)(m0 + blk * 16 + lrow) * K + k0 + lq * 8;
      async_copy16(&Ash[blk * 64], sa);
      const ushort_t* sb = Bt + (size_t)(n0 + blk * 16 + lrow) * K + k0 + lq * 8;
      async_copy16(&Bsh[blk * 64], sb);
    }
    __syncthreads();  // drains vmcnt(0): LDS staged

    short8 afr[4], bfr[4];
#pragma unroll
    for (int i = 0; i < 4; ++i) afr[i] = Ash[(4 * wm + i) * 64 + lane];
#pragma unroll
    for (int j = 0; j < 4; ++j) bfr[j] = Bsh[(4 * wn + j) * 64 + lane];
#pragma unroll
    for (int i = 0; i < 4; ++i)
#pragma unroll
      for (int j = 0; j < 4; ++j)
        acc[i][j] = __builtin_amdgcn_mfma_f32_16x16x32_bf16(afr[i], bfr[j],
                                                            acc[i][j], 0, 0, 0);
  }

  // epilogue: D row = quad*4 + r, col = lane&15 (m89-verified layout)
#pragma unroll
  for (int i = 0; i < 4; ++i) {
    int row_b = m0 + wm * 64 + i * 16 + lq * 4;
#pragma unroll
    for (int j = 0; j < 4; ++j) {
      int col = n0 + wn * 64 + j * 16 + lrow;
#pragma unroll
      for (int r = 0; r < 4; ++r)
        C[(size_t)(row_b + r) * N + col] = f2bf(acc[i][j][r]);
    }
  }
}

// ---------------------------------------------------------------------------
// alpha_src/alpha_dst: per node n, head h: sum_c h[n,h*768+c]*a[h*768+c]
// ---------------------------------------------------------------------------
template <int H>
__global__ void alpha_kernel(const ushort_t* __restrict__ Hm,
                             const float* __restrict__ aS,
                             const float* __restrict__ aD,
                             float* __restrict__ as_out,
                             float* __restrict__ ad_out) {
  const int n = blockIdx.x;
  const int t = threadIdx.x;
  const ushort_t* row = Hm + (size_t)n * (H * 768);
  float ps[H], pd[H];
#pragma unroll
  for (int h = 0; h < H; ++h) { ps[h] = 0.f; pd[h] = 0.f; }
#pragma unroll
  for (int h = 0; h < H; ++h) {
#pragma unroll
    for (int i = 0; i < 3; ++i) {
      int c = h * 768 + i * 256 + t;
      float v = bf2f(row[c]);
      ps[h] += v * aS[c];
      pd[h] += v * aD[c];
    }
  }
#pragma unroll
  for (int h = 0; h < H; ++h)
    for (int off = 32; off > 0; off >>= 1) {
      ps[h] += __shfl_down(ps[h], off, 64);
      pd[h] += __shfl_down(pd[h], off, 64);
    }
  __shared__ float red[2][4][H];
  int w = t >> 6;
  if ((t & 63) == 0) {
#pragma unroll
    for (int h = 0; h < H; ++h) { red[0][w][h] = ps[h]; red[1][w][h] = pd[h]; }
  }
  __syncthreads();
  if (t < H)
    as_out[n * H + t] = red[0][0][t] + red[0][1][t] + red[0][2][t] + red[0][3][t];
  else if (t >= 64 && t < 64 + H) {
    int h = t - 64;
    ad_out[n * H + h] = red[1][0][h] + red[1][1][h] + red[1][2][h] + red[1][3][h];
  }
}

// ---------------------------------------------------------------------------
// edge logits -> segment max (ordered-uint atomicMax)
// ---------------------------------------------------------------------------
template <int H>
__global__ void edge_max_kernel(const int* __restrict__ src,
                                const int* __restrict__ dst,
                                const float* __restrict__ as_,
                                const float* __restrict__ ad_,
                                unsigned* __restrict__ menc) {
  int gid = blockIdx.x * blockDim.x + threadIdx.x;
  if (gid >= E_TOT * H) return;
  int e = gid / H, h = gid % H;
  int s, d;
  if (e < N_EDGES) { s = src[e]; d = dst[e]; } else { s = d = e - N_EDGES; }
  float l = as_[s * H + h] + ad_[d * H + h];
  l = l > 0.f ? l : 0.2f * l;
  atomicMax(&menc[d * H + h], fenc(l));
}

// p = exp(l - max); denom += p
template <int H>
__global__ void edge_p_kernel(const int* __restrict__ src,
                              const int* __restrict__ dst,
                              const float* __restrict__ as_,
                              const float* __restrict__ ad_,
                              const unsigned* __restrict__ menc,
                              float* __restrict__ p,
                              float* __restrict__ denom) {
  int gid = blockIdx.x * blockDim.x + threadIdx.x;
  if (gid >= E_TOT * H) return;
  int e = gid / H, h = gid % H;
  int s, d;
  if (e < N_EDGES) { s = src[e]; d = dst[e]; } else { s = d = e - N_EDGES; }
  float l = as_[s * H + h] + ad_[d * H + h];
  l = l > 0.f ? l : 0.2f * l;
  float pv = __expf(l - fdec(menc[d * H + h]));
  p[e * H + h] = pv;
  atomicAdd(&denom[d * H + h], pv);
}

// ---------------------------------------------------------------------------
// CSR build: deg -> exclusive scan -> fill
// ---------------------------------------------------------------------------
__global__ void deg_kernel(const int* __restrict__ dst, int* __restrict__ deg) {
  int e = blockIdx.x * blockDim.x + threadIdx.x;
  if (e >= E_TOT) return;
  int d = (e < N_EDGES) ? dst[e] : (e - N_EDGES);
  atomicAdd(&deg[d], 1);
}

__global__ void scan_kernel(const int* __restrict__ deg, int* __restrict__ start,
                            int* __restrict__ cursor) {
  __shared__ int sums[1024];
  int t = threadIdx.x;
  int base = t * 8;
  int local[8];
  int s = 0;
#pragma unroll
  for (int i = 0; i < 8; ++i) { local[i] = s; s += deg[base + i]; }
  sums[t] = s;
  __syncthreads();
  for (int off = 1; off < 1024; off <<= 1) {
    int v = (t >= off) ? sums[t - off] : 0;
    __syncthreads();
    sums[t] += v;
    __syncthreads();
  }
  int excl = (t == 0) ? 0 : sums[t - 1];
#pragma unroll
  for (int i = 0; i < 8; ++i) {
    int st = excl + local[i];
    start[base + i] = st;
    cursor[base + i] = st;
  }
}

__global__ void fill_kernel(const int* __restrict__ dst, int* __restrict__ cursor,
                            int* __restrict__ csr) {
  int e = blockIdx.x * blockDim.x + threadIdx.x;
  if (e >= E_TOT) return;
  int d = (e < N_EDGES) ? dst[e] : (e - N_EDGES);
  int pos = atomicAdd(&cursor[d], 1);
  csr[pos] = e;
}

// ---------------------------------------------------------------------------
// Layer-1 aggregation: out[n,h,c] = sum_e alpha * h1[src_e, h, c], +b1, ELU,
// store bf16. Thread t owns 24 contiguous channels [t*24, t*24+24) -> its head
// (t>>5) is uniform; 3x16B vector gathers per edge.
// ---------------------------------------------------------------------------
__global__ __launch_bounds__(256) void aggregate1_kernel(
    const ushort_t* __restrict__ h1, const float* __restrict__ p,
    const float* __restrict__ denom, const int* __restrict__ start,
    const int* __restrict__ deg, const int* __restrict__ csr,
    const int* __restrict__ src, const float* __restrict__ b1,
    ushort_t* __restrict__ h2) {
  const int n = blockIdx.x;
  const int t = threadIdx.x;
  const int head = t >> 5;
  const int cbase = t * 24;
  const float invd = 1.0f / denom[n * 8 + head];
  float acc[24];
#pragma unroll
  for (int i = 0; i < 24; ++i) acc[i] = 0.f;

  const int st = start[n], dg = deg[n];
  for (int ei = 0; ei < dg; ++ei) {
    int e = csr[st + ei];
    int s = (e < N_EDGES) ? src[e] : (e - N_EDGES);
    float alpha = p[e * 8 + head] * invd;
    const uint4* r4 = (const uint4*)(h1 + (size_t)s * HC1 + cbase);
#pragma unroll
    for (int v = 0; v < 3; ++v) {
      uint4 dv = r4[v];
      unsigned uu[4] = {dv.x, dv.y, dv.z, dv.w};
#pragma unroll
      for (int q = 0; q < 4; ++q) {
        acc[v * 8 + 2 * q]     += alpha * __uint_as_float(uu[q] << 16);
        acc[v * 8 + 2 * q + 1] += alpha * __uint_as_float(uu[q] & 0xffff0000u);
      }
    }
  }
  const float* b1p = b1 + cbase;
  uint4 outv[3];
#pragma unroll
  for (int v = 0; v < 3; ++v) {
    unsigned words[4];
#pragma unroll
    for (int q = 0; q < 4; ++q) {
      int i = v * 8 + 2 * q;
      float lo = acc[i] + b1p[i];
      float hi = acc[i + 1] + b1p[i + 1];
      lo = lo > 0.f ? lo : expm1f(lo);  // ELU
      hi = hi > 0.f ? hi : expm1f(hi);
      words[q] = (unsigned)f2bf(lo) | ((unsigned)f2bf(hi) << 16);
    }
    outv[v] = make_uint4(words[0], words[1], words[2], words[3]);
  }
  uint4* o4 = (uint4*)(h2 + (size_t)n * HC1 + cbase);
  o4[0] = outv[0]; o4[1] = outv[1]; o4[2] = outv[2];
}

// ---------------------------------------------------------------------------
// Layer-2 aggregation (H=1): out[n,c] = sum_e alpha * y[src_e, c] + b2 (fp32)
// ---------------------------------------------------------------------------
__global__ __launch_bounds__(256) void aggregate2_kernel(
    const ushort_t* __restrict__ yb, const float* __restrict__ p2,
    const float* __restrict__ denom2, const int* __restrict__ start,
    const int* __restrict__ deg, const int* __restrict__ csr,
    const int* __restrict__ src, const float* __restrict__ b2,
    float* __restrict__ out) {
  const int n = blockIdx.x;
  const int t = threadIdx.x;
  const float invd = 1.0f / denom2[n];
  float a0 = 0.f, a1 = 0.f, a2 = 0.f;
  const int st = start[n], dg = deg[n];
  for (int ei = 0; ei < dg; ++ei) {
    int e = csr[st + ei];
    int s = (e < N_EDGES) ? src[e] : (e - N_EDGES);
    float alpha = p2[e] * invd;
    const ushort_t* row = yb + (size_t)s * 768;
    a0 += alpha * bf2f(row[t]);
    a1 += alpha * bf2f(row[t + 256]);
    a2 += alpha * bf2f(row[t + 512]);
  }
  out[(size_t)n * 768 + t]       = a0 + b2[t];
  out[(size_t)n * 768 + t + 256] = a1 + b2[t + 256];
  out[(size_t)n * 768 + t + 512] = a2 + b2[t + 512];
}

// ---------------------------------------------------------------------------
extern "C" void kernel_launch(void* const* d_in, const int* in_sizes, int n_in,
                              void* d_out, int out_size, void* d_ws, size_t ws_size,
                              hipStream_t stream) {
  const float* x      = (const float*)d_in[0];
  const int*   ei     = (const int*)d_in[1];
  const float* W1     = (const float*)d_in[2];
  const float* a_src1 = (const float*)d_in[3];
  const float* a_dst1 = (const float*)d_in[4];
  const float* b1     = (const float*)d_in[5];
  const float* W2     = (const float*)d_in[6];
  const float* a_src2 = (const float*)d_in[7];
  const float* a_dst2 = (const float*)d_in[8];
  const float* b2     = (const float*)d_in[9];
  float* out = (float*)d_out;
  const int* src = ei;
  const int* dst = ei + N_EDGES;

  char* ws = (char*)d_ws;
  size_t off = 0;
  auto alloc = [&](size_t bytes) -> void* {
    void* p = ws + off;
    off = (off + bytes + 255) & ~(size_t)255;
    return p;
  };

  // --- zero-init block (contiguous; sizes all multiples of 256) ---
  char* zero_base = (char*)(ws + off);
  unsigned* menc1 = (unsigned*)alloc(N_NODES * H1 * 4);   // enc(0)=min sentinel
  float* denom1   = (float*)alloc(N_NODES * H1 * 4);
  unsigned* menc2 = (unsigned*)alloc(N_NODES * 4);
  float* denom2   = (float*)alloc(N_NODES * 4);
  int* deg        = (int*)alloc(N_NODES * 4);
  size_t zero_bytes = (char*)(ws + off) - zero_base;

  float* as1 = (float*)alloc(N_NODES * H1 * 4);
  float* ad1 = (float*)alloc(N_NODES * H1 * 4);
  float* as2 = (float*)alloc(N_NODES * 4);
  float* ad2 = (float*)alloc(N_NODES * 4);
  float* p1  = (float*)alloc((size_t)E_TOT * H1 * 4);
  float* p2  = (float*)alloc((size_t)E_TOT * 4);
  int* start  = (int*)alloc(N_NODES * 4);
  int* cursor = (int*)alloc(N_NODES * 4);
  int* csr    = (int*)alloc(E_TOT * 4);
  ushort_t* xb  = (ushort_t*)alloc((size_t)N_NODES * D_IN * 2);  // reused as yb
  ushort_t* w1t = (ushort_t*)alloc((size_t)HC1 * D_IN * 2);      // reused as w2t
  ushort_t* h1  = (ushort_t*)alloc((size_t)N_NODES * HC1 * 2);
  ushort_t* h2b = (ushort_t*)alloc((size_t)N_NODES * HC1 * 2);
  ushort_t* yb  = xb;   // xb dead after gemm1
  ushort_t* w2t = w1t;  // w1t dead after gemm1
  (void)ws_size; (void)n_in; (void)in_sizes; (void)out_size;

  hipMemsetAsync(zero_base, 0, zero_bytes, stream);

  // x -> bf16
  convert_bf16_kernel<<<(N_NODES * D_IN / 4 + 255) / 256, 256, 0, stream>>>(
      x, xb, N_NODES * D_IN / 4);
  // W1 [768][6144] -> w1t [6144][768] bf16
  transpose_f2b_kernel<<<dim3(HC1 / 32, D_IN / 32), dim3(32, 8), 0, stream>>>(
      W1, w1t, D_IN, HC1);
  // gemm1: h1[8192][6144] = xb @ w1t^T
  gemm_bf16_kernel<<<dim3(HC1 / 128, N_NODES / 128), 256, 0, stream>>>(
      xb, w1t, h1, N_NODES, HC1, D_IN);
  // W2 [6144][768] -> w2t [768][6144] (after gemm1: aliases w1t)
  transpose_f2b_kernel<<<dim3(D_IN / 32, HC1 / 32), dim3(32, 8), 0, stream>>>(
      W2, w2t, HC1, D_IN);

  // CSR build (graph identical for both layers)
  deg_kernel<<<(E_TOT + 255) / 256, 256, 0, stream>>>(dst, deg);
  scan_kernel<<<1, 1024, 0, stream>>>(deg, start, cursor);
  fill_kernel<<<(E_TOT + 255) / 256, 256, 0, stream>>>(dst, cursor, csr);

  // layer-1 attention
  alpha_kernel<H1><<<N_NODES, 256, 0, stream>>>(h1, a_src1, a_dst1, as1, ad1);
  edge_max_kernel<H1><<<(E_TOT * H1 + 255) / 256, 256, 0, stream>>>(
      src, dst, as1, ad1, menc1);
  edge_p_kernel<H1><<<(E_TOT * H1 + 255) / 256, 256, 0, stream>>>(
      src, dst, as1, ad1, menc1, p1, denom1);
  aggregate1_kernel<<<N_NODES, 256, 0, stream>>>(h1, p1, denom1, start, deg,
                                                 csr, src, b1, h2b);

  // gemm2: yb[8192][768] = h2b @ w2t^T
  gemm_bf16_kernel<<<dim3(D_IN / 128, N_NODES / 128), 256, 0, stream>>>(
      h2b, w2t, yb, N_NODES, D_IN, HC1);

  // layer-2 attention
  alpha_kernel<1><<<N_NODES, 256, 0, stream>>>(yb, a_src2, a_dst2, as2, ad2);
  edge_max_kernel<1><<<(E_TOT + 255) / 256, 256, 0, stream>>>(
      src, dst, as2, ad2, menc2);
  edge_p_kernel<1><<<(E_TOT + 255) / 256, 256, 0, stream>>>(
      src, dst, as2, ad2, menc2, p2, denom2);
  aggregate2_kernel<<<N_NODES, 256, 0, stream>>>(yb, p2, denom2, start, deg,
                                                 csr, src, b2, out);
}

// Round 2
// 586.139 us; speedup vs baseline: 1.1189x; 1.1189x over previous
//
#include <hip/hip_runtime.h>
#include <hip/hip_bf16.h>

// ---------------------------------------------------------------------------
// GAT 2-layer model on MI355X — round 2.
// Layer1 commuted: z[n,h,:] = sum_e alpha_{e,h} x[src_e,:]  (63MB gather)
//                  h2 = ELU(z_h @ W1_h + b1)                (batched MFMA GEMM)
//                  alpha logits from x via precomputed W1_h @ a_vec.
// Layer2: y = h2@W2 split-K=4 MFMA -> reduce -> 1-head attention -> +b2.
// ---------------------------------------------------------------------------

#define N_NODES 8192
#define N_EDGES 32768
#define E_TOT   (N_EDGES + N_NODES)   // self-loops appended
#define D_IN    768
#define H1      8
#define HC1     (H1 * D_IN)           // 6144
#define KSPLIT  4
#define KSLICE  (HC1 / KSPLIT)        // 1536

typedef unsigned short ushort_t;
using short8  = __attribute__((ext_vector_type(8))) short;
using floatx4 = __attribute__((ext_vector_type(4))) float;

__device__ __forceinline__ float bf2f(unsigned short u) {
  return __uint_as_float(((unsigned)u) << 16);
}
__device__ __forceinline__ unsigned short f2bf(float f) {
  unsigned u = __float_as_uint(f);
  unsigned r = (u + 0x7fffu + ((u >> 16) & 1u)) >> 16;  // RNE
  return (unsigned short)r;
}
// order-preserving float<->uint for atomicMax on floats (incl. negatives)
__device__ __forceinline__ unsigned fenc(float f) {
  unsigned u = __float_as_uint(f);
  return (u & 0x80000000u) ? ~u : (u | 0x80000000u);
}
__device__ __forceinline__ float fdec(unsigned u) {
  return __uint_as_float((u & 0x80000000u) ? (u ^ 0x80000000u) : ~u);
}

__device__ __forceinline__ void async_copy16(void* lds, const void* g) {
  __builtin_amdgcn_global_load_lds(
      (__attribute__((address_space(1))) void*)(g),
      (__attribute__((address_space(3))) void*)(lds), 16, 0, 0);
}

// ---------------------------------------------------------------------------
// fp32 [R][C] -> bf16 transpose [C][R]
// ---------------------------------------------------------------------------
__global__ void transpose_f2b_kernel(const float* __restrict__ in,
                                     ushort_t* __restrict__ out, int R, int C) {
  __shared__ float tile[32][33];
  int bx = blockIdx.x * 32;
  int by = blockIdx.y * 32;
  int tx = threadIdx.x, ty = threadIdx.y;  // (32, 8)
#pragma unroll
  for (int i = 0; i < 32; i += 8)
    tile[ty + i][tx] = in[(size_t)(by + ty + i) * C + bx + tx];
  __syncthreads();
#pragma unroll
  for (int i = 0; i < 32; i += 8)
    out[(size_t)(bx + ty + i) * R + by + tx] = f2bf(tile[tx][ty + i]);
}

// ---------------------------------------------------------------------------
// awS[d][h] = sum_c W1[d][h*768+c]*a_src1[h*768+c]; awD likewise. d=blockIdx.
// ---------------------------------------------------------------------------
__global__ void prep_aw_kernel(const float* __restrict__ W1,
                               const float* __restrict__ aS,
                               const float* __restrict__ aD,
                               float* __restrict__ awS,
                               float* __restrict__ awD) {
  const int d = blockIdx.x;
  const int t = threadIdx.x;
  const float* row = W1 + (size_t)d * HC1;
  float ps[H1], pd[H1];
#pragma unroll
  for (int h = 0; h < H1; ++h) { ps[h] = 0.f; pd[h] = 0.f; }
#pragma unroll
  for (int h = 0; h < H1; ++h)
#pragma unroll
    for (int j = 0; j < 3; ++j) {
      int idx = h * 768 + j * 256 + t;
      float w = row[idx];
      ps[h] += w * aS[idx];
      pd[h] += w * aD[idx];
    }
#pragma unroll
  for (int h = 0; h < H1; ++h)
    for (int off = 32; off > 0; off >>= 1) {
      ps[h] += __shfl_down(ps[h], off, 64);
      pd[h] += __shfl_down(pd[h], off, 64);
    }
  __shared__ float red[2][4][H1];
  int w = t >> 6;
  if ((t & 63) == 0) {
#pragma unroll
    for (int h = 0; h < H1; ++h) { red[0][w][h] = ps[h]; red[1][w][h] = pd[h]; }
  }
  __syncthreads();
  if (t < H1)
    awS[d * H1 + t] = red[0][0][t] + red[0][1][t] + red[0][2][t] + red[0][3][t];
  else if (t >= 64 && t < 64 + H1) {
    int h = t - 64;
    awD[d * H1 + h] = red[1][0][h] + red[1][1][h] + red[1][2][h] + red[1][3][h];
  }
}

// ---------------------------------------------------------------------------
// per node: xb = bf16(x); as1[n,h] = x[n,:]@awS[:,h]; ad1 likewise.
// ---------------------------------------------------------------------------
__global__ void node_prep_kernel(const float* __restrict__ x,
                                 const float* __restrict__ awS,
                                 const float* __restrict__ awD,
                                 ushort_t* __restrict__ xb,
                                 float* __restrict__ as1,
                                 float* __restrict__ ad1) {
  const int n = blockIdx.x;
  const int t = threadIdx.x;
  float ps[H1], pd[H1];
#pragma unroll
  for (int h = 0; h < H1; ++h) { ps[h] = 0.f; pd[h] = 0.f; }
#pragma unroll
  for (int j = 0; j < 3; ++j) {
    int d = j * 256 + t;
    float xv = x[(size_t)n * 768 + d];
    xb[(size_t)n * 768 + d] = f2bf(xv);
    const float4* s4 = (const float4*)(awS + d * 8);
    const float4* d4 = (const float4*)(awD + d * 8);
    float4 a0 = s4[0], a1 = s4[1];
    float4 c0 = d4[0], c1 = d4[1];
    ps[0] += xv * a0.x; ps[1] += xv * a0.y; ps[2] += xv * a0.z; ps[3] += xv * a0.w;
    ps[4] += xv * a1.x; ps[5] += xv * a1.y; ps[6] += xv * a1.z; ps[7] += xv * a1.w;
    pd[0] += xv * c0.x; pd[1] += xv * c0.y; pd[2] += xv * c0.z; pd[3] += xv * c0.w;
    pd[4] += xv * c1.x; pd[5] += xv * c1.y; pd[6] += xv * c1.z; pd[7] += xv * c1.w;
  }
#pragma unroll
  for (int h = 0; h < H1; ++h)
    for (int off = 32; off > 0; off >>= 1) {
      ps[h] += __shfl_down(ps[h], off, 64);
      pd[h] += __shfl_down(pd[h], off, 64);
    }
  __shared__ float red[2][4][H1];
  int w = t >> 6;
  if ((t & 63) == 0) {
#pragma unroll
    for (int h = 0; h < H1; ++h) { red[0][w][h] = ps[h]; red[1][w][h] = pd[h]; }
  }
  __syncthreads();
  if (t < H1)
    as1[n * H1 + t] = red[0][0][t] + red[0][1][t] + red[0][2][t] + red[0][3][t];
  else if (t >= 64 && t < 64 + H1) {
    int h = t - 64;
    ad1[n * H1 + h] = red[1][0][h] + red[1][1][h] + red[1][2][h] + red[1][3][h];
  }
}

// ---------------------------------------------------------------------------
// alpha (H=1) for layer 2: dot of yb row with a_src2/a_dst2
// ---------------------------------------------------------------------------
__global__ void alpha2_kernel(const ushort_t* __restrict__ Hm,
                              const float* __restrict__ aS,
                              const float* __restrict__ aD,
                              float* __restrict__ as_out,
                              float* __restrict__ ad_out) {
  const int n = blockIdx.x;
  const int t = threadIdx.x;
  const ushort_t* row = Hm + (size_t)n * 768;
  float ps = 0.f, pd = 0.f;
#pragma unroll
  for (int i = 0; i < 3; ++i) {
    int c = i * 256 + t;
    float v = bf2f(row[c]);
    ps += v * aS[c];
    pd += v * aD[c];
  }
  for (int off = 32; off > 0; off >>= 1) {
    ps += __shfl_down(ps, off, 64);
    pd += __shfl_down(pd, off, 64);
  }
  __shared__ float red[2][4];
  int w = t >> 6;
  if ((t & 63) == 0) { red[0][w] = ps; red[1][w] = pd; }
  __syncthreads();
  if (t == 0) as_out[n] = red[0][0] + red[0][1] + red[0][2] + red[0][3];
  if (t == 64) ad_out[n] = red[1][0] + red[1][1] + red[1][2] + red[1][3];
}

// ---------------------------------------------------------------------------
// edge logits -> segment max (ordered-uint atomicMax); then p/denom
// ---------------------------------------------------------------------------
template <int H>
__global__ void edge_max_kernel(const int* __restrict__ src,
                                const int* __restrict__ dst,
                                const float* __restrict__ as_,
                                const float* __restrict__ ad_,
                                unsigned* __restrict__ menc) {
  int gid = blockIdx.x * blockDim.x + threadIdx.x;
  if (gid >= E_TOT * H) return;
  int e = gid / H, h = gid % H;
  int s, d;
  if (e < N_EDGES) { s = src[e]; d = dst[e]; } else { s = d = e - N_EDGES; }
  float l = as_[s * H + h] + ad_[d * H + h];
  l = l > 0.f ? l : 0.2f * l;
  atomicMax(&menc[d * H + h], fenc(l));
}

template <int H>
__global__ void edge_p_kernel(const int* __restrict__ src,
                              const int* __restrict__ dst,
                              const float* __restrict__ as_,
                              const float* __restrict__ ad_,
                              const unsigned* __restrict__ menc,
                              float* __restrict__ p,
                              float* __restrict__ denom) {
  int gid = blockIdx.x * blockDim.x + threadIdx.x;
  if (gid >= E_TOT * H) return;
  int e = gid / H, h = gid % H;
  int s, d;
  if (e < N_EDGES) { s = src[e]; d = dst[e]; } else { s = d = e - N_EDGES; }
  float l = as_[s * H + h] + ad_[d * H + h];
  l = l > 0.f ? l : 0.2f * l;
  float pv = __expf(l - fdec(menc[d * H + h]));
  p[e * H + h] = pv;
  atomicAdd(&denom[d * H + h], pv);
}

// ---------------------------------------------------------------------------
// CSR build: deg -> exclusive scan -> fill
// ---------------------------------------------------------------------------
__global__ void deg_kernel(const int* __restrict__ dst, int* __restrict__ deg) {
  int e = blockIdx.x * blockDim.x + threadIdx.x;
  if (e >= E_TOT) return;
  int d = (e < N_EDGES) ? dst[e] : (e - N_EDGES);
  atomicAdd(&deg[d], 1);
}

__global__ void scan_kernel(const int* __restrict__ deg, int* __restrict__ start,
                            int* __restrict__ cursor) {
  __shared__ int sums[1024];
  int t = threadIdx.x;
  int base = t * 8;
  int local[8];
  int s = 0;
#pragma unroll
  for (int i = 0; i < 8; ++i) { local[i] = s; s += deg[base + i]; }
  sums[t] = s;
  __syncthreads();
  for (int off = 1; off < 1024; off <<= 1) {
    int v = (t >= off) ? sums[t - off] : 0;
    __syncthreads();
    sums[t] += v;
    __syncthreads();
  }
  int excl = (t == 0) ? 0 : sums[t - 1];
#pragma unroll
  for (int i = 0; i < 8; ++i) {
    int st = excl + local[i];
    start[base + i] = st;
    cursor[base + i] = st;
  }
}

__global__ void fill_kernel(const int* __restrict__ dst, int* __restrict__ cursor,
                            int* __restrict__ csr) {
  int e = blockIdx.x * blockDim.x + threadIdx.x;
  if (e >= E_TOT) return;
  int d = (e < N_EDGES) ? dst[e] : (e - N_EDGES);
  int pos = atomicAdd(&cursor[d], 1);
  csr[pos] = e;
}

// ---------------------------------------------------------------------------
// z[n,h,c] = sum_e alpha_{e,h} * xb[src_e, c]  (bf16 out, [N][H][768])
// ---------------------------------------------------------------------------
__global__ __launch_bounds__(256) void aggregate_z_kernel(
    const ushort_t* __restrict__ xb, const float* __restrict__ p1,
    const float* __restrict__ denom1, const int* __restrict__ start,
    const int* __restrict__ deg, const int* __restrict__ csr,
    const int* __restrict__ src, ushort_t* __restrict__ z) {
  const int n = blockIdx.x;
  const int t = threadIdx.x;
  float invd[H1];
#pragma unroll
  for (int h = 0; h < H1; ++h) invd[h] = 1.0f / denom1[n * H1 + h];
  float acc[H1][3];
#pragma unroll
  for (int h = 0; h < H1; ++h)
#pragma unroll
    for (int j = 0; j < 3; ++j) acc[h][j] = 0.f;

  const int st = start[n], dg = deg[n];
  for (int ei = 0; ei < dg; ++ei) {
    int e = csr[st + ei];
    int s = (e < N_EDGES) ? src[e] : (e - N_EDGES);
    float al[H1];
#pragma unroll
    for (int h = 0; h < H1; ++h) al[h] = p1[e * H1 + h] * invd[h];
    float xv[3];
#pragma unroll
    for (int j = 0; j < 3; ++j) xv[j] = bf2f(xb[(size_t)s * 768 + j * 256 + t]);
#pragma unroll
    for (int h = 0; h < H1; ++h)
#pragma unroll
      for (int j = 0; j < 3; ++j) acc[h][j] += al[h] * xv[j];
  }
#pragma unroll
  for (int h = 0; h < H1; ++h)
#pragma unroll
    for (int j = 0; j < 3; ++j)
      z[(size_t)n * HC1 + h * 768 + j * 256 + t] = f2bf(acc[h][j]);
}

// ---------------------------------------------------------------------------
// Batched per-head GEMM (layer1): h2b_h = ELU(z_h @ W1_h^T(bt) + b1_h), bf16.
// 128x128 tile, BK=32, m97-style fragment-ordered LDS staging.
// ---------------------------------------------------------------------------
__global__ __launch_bounds__(256) void gemm_l1_kernel(
    const ushort_t* __restrict__ Ab, const ushort_t* __restrict__ Btb,
    const float* __restrict__ biasb, ushort_t* __restrict__ Cb) {
  __shared__ short8 Ash[512];
  __shared__ short8 Bsh[512];
  const int head = blockIdx.z;
  const ushort_t* A  = Ab + head * 768;                   // lda = HC1
  const ushort_t* Bt = Btb + (size_t)head * 768 * 768;    // ldb = 768
  const float* bias  = biasb + head * 768;
  ushort_t* C        = Cb + head * 768;                   // ldc = HC1
  const int tid = threadIdx.x;
  const int lane = tid & 63;
  const int w = tid >> 6;
  const int wm = w >> 1, wn = w & 1;
  const int m0 = blockIdx.y * 128;
  const int n0 = blockIdx.x * 128;
  const int lrow = lane & 15;
  const int lq = lane >> 4;

  floatx4 acc[4][4];
#pragma unroll
  for (int i = 0; i < 4; ++i)
#pragma unroll
    for (int j = 0; j < 4; ++j) acc[i][j] = {0.f, 0.f, 0.f, 0.f};

  for (int k0 = 0; k0 < 768; k0 += 32) {
    __syncthreads();
#pragma unroll
    for (int ii = 0; ii < 2; ++ii) {
      int blk = 2 * w + ii;
      const ushort_t* sa = A + (size_t)(m0 + blk * 16 + lrow) * HC1 + k0 + lq * 8;
      async_copy16(&Ash[blk * 64], sa);
      const ushort_t* sb = Bt + (size_t)(n0 + blk * 16 + lrow) * 768 + k0 + lq * 8;
      async_copy16(&Bsh[blk * 64], sb);
    }
    __syncthreads();

    short8 afr[4], bfr[4];
#pragma unroll
    for (int i = 0; i < 4; ++i) afr[i] = Ash[(4 * wm + i) * 64 + lane];
#pragma unroll
    for (int j = 0; j < 4; ++j) bfr[j] = Bsh[(4 * wn + j) * 64 + lane];
#pragma unroll
    for (int i = 0; i < 4; ++i)
#pragma unroll
      for (int j = 0; j < 4; ++j)
        acc[i][j] = __builtin_amdgcn_mfma_f32_16x16x32_bf16(afr[i], bfr[j],
                                                            acc[i][j], 0, 0, 0);
  }

#pragma unroll
  for (int i = 0; i < 4; ++i) {
    int row_b = m0 + wm * 64 + i * 16 + lq * 4;
#pragma unroll
    for (int j = 0; j < 4; ++j) {
      int col = n0 + wn * 64 + j * 16 + lrow;
      float bv = bias[col];
#pragma unroll
      for (int r = 0; r < 4; ++r) {
        float v = acc[i][j][r] + bv;
        v = v > 0.f ? v : expm1f(v);  // ELU
        C[(size_t)(row_b + r) * HC1 + col] = f2bf(v);
      }
    }
  }
}

// ---------------------------------------------------------------------------
// Layer-2 GEMM split-K: partial_s = h2b[:, sK:(s+1)K] @ w2t^T slice, fp32.
// ---------------------------------------------------------------------------
__global__ __launch_bounds__(256) void gemm_l2_kernel(
    const ushort_t* __restrict__ A, const ushort_t* __restrict__ Bt,
    float* __restrict__ Cp) {
  __shared__ short8 Ash[512];
  __shared__ short8 Bsh[512];
  const int s = blockIdx.z;
  const int kbase = s * KSLICE;
  float* C = Cp + (size_t)s * N_NODES * 768;
  const int tid = threadIdx.x;
  const int lane = tid & 63;
  const int w = tid >> 6;
  const int wm = w >> 1, wn = w & 1;
  const int m0 = blockIdx.y * 128;
  const int n0 = blockIdx.x * 128;
  const int lrow = lane & 15;
  const int lq = lane >> 4;

  floatx4 acc[4][4];
#pragma unroll
  for (int i = 0; i < 4; ++i)
#pragma unroll
    for (int j = 0; j < 4; ++j) acc[i][j] = {0.f, 0.f, 0.f, 0.f};

  for (int k0 = kbase; k0 < kbase + KSLICE; k0 += 32) {
    __syncthreads();
#pragma unroll
    for (int ii = 0; ii < 2; ++ii) {
      int blk = 2 * w + ii;
      const ushort_t* sa = A + (size_t)(m0 + blk * 16 + lrow) * HC1 + k0 + lq * 8;
      async_copy16(&Ash[blk * 64], sa);
      const ushort_t* sb = Bt + (size_t)(n0 + blk * 16 + lrow) * HC1 + k0 + lq * 8;
      async_copy16(&Bsh[blk * 64], sb);
    }
    __syncthreads();

    short8 afr[4], bfr[4];
#pragma unroll
    for (int i = 0; i < 4; ++i) afr[i] = Ash[(4 * wm + i) * 64 + lane];
#pragma unroll
    for (int j = 0; j < 4; ++j) bfr[j] = Bsh[(4 * wn + j) * 64 + lane];
#pragma unroll
    for (int i = 0; i < 4; ++i)
#pragma unroll
      for (int j = 0; j < 4; ++j)
        acc[i][j] = __builtin_amdgcn_mfma_f32_16x16x32_bf16(afr[i], bfr[j],
                                                            acc[i][j], 0, 0, 0);
  }

#pragma unroll
  for (int i = 0; i < 4; ++i) {
    int row_b = m0 + wm * 64 + i * 16 + lq * 4;
#pragma unroll
    for (int j = 0; j < 4; ++j) {
      int col = n0 + wn * 64 + j * 16 + lrow;
#pragma unroll
      for (int r = 0; r < 4; ++r)
        C[(size_t)(row_b + r) * 768 + col] = acc[i][j][r];
    }
  }
}

// yb = bf16(sum of 4 partials)
__global__ void reduce4_kernel(const float* __restrict__ p,
                               ushort_t* __restrict__ yb) {
  const size_t S = (size_t)N_NODES * 768 / 4;
  size_t i = blockIdx.x * blockDim.x + threadIdx.x;
  const float4* p4 = (const float4*)p;
  float4 v0 = p4[i], v1 = p4[i + S], v2 = p4[i + 2 * S], v3 = p4[i + 3 * S];
  ushort_t r[4] = {f2bf(v0.x + v1.x + v2.x + v3.x),
                   f2bf(v0.y + v1.y + v2.y + v3.y),
                   f2bf(v0.z + v1.z + v2.z + v3.z),
                   f2bf(v0.w + v1.w + v2.w + v3.w)};
  ((ushort4*)yb)[i] = *(ushort4*)r;
}

// ---------------------------------------------------------------------------
// Layer-2 aggregation (H=1): out[n,c] = sum_e alpha * y[src_e, c] + b2 (fp32)
// ---------------------------------------------------------------------------
__global__ __launch_bounds__(256) void aggregate2_kernel(
    const ushort_t* __restrict__ yb, const float* __restrict__ p2,
    const float* __restrict__ denom2, const int* __restrict__ start,
    const int* __restrict__ deg, const int* __restrict__ csr,
    const int* __restrict__ src, const float* __restrict__ b2,
    float* __restrict__ out) {
  const int n = blockIdx.x;
  const int t = threadIdx.x;
  const float invd = 1.0f / denom2[n];
  float a0 = 0.f, a1 = 0.f, a2 = 0.f;
  const int st = start[n], dg = deg[n];
  for (int ei = 0; ei < dg; ++ei) {
    int e = csr[st + ei];
    int s = (e < N_EDGES) ? src[e] : (e - N_EDGES);
    float alpha = p2[e] * invd;
    const ushort_t* row = yb + (size_t)s * 768;
    a0 += alpha * bf2f(row[t]);
    a1 += alpha * bf2f(row[t + 256]);
    a2 += alpha * bf2f(row[t + 512]);
  }
  out[(size_t)n * 768 + t]       = a0 + b2[t];
  out[(size_t)n * 768 + t + 256] = a1 + b2[t + 256];
  out[(size_t)n * 768 + t + 512] = a2 + b2[t + 512];
}

// ---------------------------------------------------------------------------
extern "C" void kernel_launch(void* const* d_in, const int* in_sizes, int n_in,
                              void* d_out, int out_size, void* d_ws, size_t ws_size,
                              hipStream_t stream) {
  const float* x      = (const float*)d_in[0];
  const int*   ei     = (const int*)d_in[1];
  const float* W1     = (const float*)d_in[2];
  const float* a_src1 = (const float*)d_in[3];
  const float* a_dst1 = (const float*)d_in[4];
  const float* b1     = (const float*)d_in[5];
  const float* W2     = (const float*)d_in[6];
  const float* a_src2 = (const float*)d_in[7];
  const float* a_dst2 = (const float*)d_in[8];
  const float* b2     = (const float*)d_in[9];
  float* out = (float*)d_out;
  const int* src = ei;
  const int* dst = ei + N_EDGES;

  char* ws = (char*)d_ws;
  size_t off = 0;
  auto alloc = [&](size_t bytes) -> void* {
    void* p = ws + off;
    off = (off + bytes + 255) & ~(size_t)255;
    return p;
  };

  // --- zero-init block ---
  char* zero_base = (char*)(ws + off);
  unsigned* menc1 = (unsigned*)alloc(N_NODES * H1 * 4);
  float* denom1   = (float*)alloc(N_NODES * H1 * 4);
  unsigned* menc2 = (unsigned*)alloc(N_NODES * 4);
  float* denom2   = (float*)alloc(N_NODES * 4);
  int* deg        = (int*)alloc(N_NODES * 4);
  size_t zero_bytes = (char*)(ws + off) - zero_base;

  float* awS = (float*)alloc(768 * H1 * 4);
  float* awD = (float*)alloc(768 * H1 * 4);
  float* as1 = (float*)alloc(N_NODES * H1 * 4);
  float* ad1 = (float*)alloc(N_NODES * H1 * 4);
  float* as2 = (float*)alloc(N_NODES * 4);
  float* ad2 = (float*)alloc(N_NODES * 4);
  float* p1  = (float*)alloc((size_t)E_TOT * H1 * 4);
  float* p2  = (float*)alloc((size_t)E_TOT * 4);
  int* start  = (int*)alloc(N_NODES * 4);
  int* cursor = (int*)alloc(N_NODES * 4);
  int* csr    = (int*)alloc(E_TOT * 4);
  ushort_t* xb  = (ushort_t*)alloc((size_t)N_NODES * D_IN * 2);  // -> yb later
  ushort_t* w1t = (ushort_t*)alloc((size_t)HC1 * D_IN * 2);
  ushort_t* w2t = (ushort_t*)alloc((size_t)HC1 * D_IN * 2);
  ushort_t* z   = (ushort_t*)alloc((size_t)N_NODES * HC1 * 2);   // -> partials
  ushort_t* h2b = (ushort_t*)alloc((size_t)N_NODES * HC1 * 2);
  ushort_t* yb  = xb;          // xb dead after aggregate_z
  float* parts  = (float*)z;   // z dead after gemm_l1 (same byte size)
  (void)ws_size; (void)n_in; (void)in_sizes; (void)out_size;

  hipMemsetAsync(zero_base, 0, zero_bytes, stream);

  // weight prep
  prep_aw_kernel<<<768, 256, 0, stream>>>(W1, a_src1, a_dst1, awS, awD);
  node_prep_kernel<<<N_NODES, 256, 0, stream>>>(x, awS, awD, xb, as1, ad1);
  transpose_f2b_kernel<<<dim3(HC1 / 32, D_IN / 32), dim3(32, 8), 0, stream>>>(
      W1, w1t, D_IN, HC1);  // [6144][768]
  transpose_f2b_kernel<<<dim3(D_IN / 32, HC1 / 32), dim3(32, 8), 0, stream>>>(
      W2, w2t, HC1, D_IN);  // [768][6144]

  // CSR build (graph identical for both layers)
  deg_kernel<<<(E_TOT + 255) / 256, 256, 0, stream>>>(dst, deg);
  scan_kernel<<<1, 1024, 0, stream>>>(deg, start, cursor);
  fill_kernel<<<(E_TOT + 255) / 256, 256, 0, stream>>>(dst, cursor, csr);

  // layer-1 attention on x-derived logits
  edge_max_kernel<H1><<<(E_TOT * H1 + 255) / 256, 256, 0, stream>>>(
      src, dst, as1, ad1, menc1);
  edge_p_kernel<H1><<<(E_TOT * H1 + 255) / 256, 256, 0, stream>>>(
      src, dst, as1, ad1, menc1, p1, denom1);
  aggregate_z_kernel<<<N_NODES, 256, 0, stream>>>(xb, p1, denom1, start, deg,
                                                  csr, src, z);
  // batched per-head GEMM with fused bias+ELU
  gemm_l1_kernel<<<dim3(6, 64, H1), 256, 0, stream>>>(z, w1t, b1, h2b);

  // layer-2 GEMM split-K=4 + reduce
  gemm_l2_kernel<<<dim3(6, 64, KSPLIT), 256, 0, stream>>>(h2b, w2t, parts);
  reduce4_kernel<<<(N_NODES * 768 / 4) / 256, 256, 0, stream>>>(parts, yb);

  // layer-2 attention
  alpha2_kernel<<<N_NODES, 256, 0, stream>>>(yb, a_src2, a_dst2, as2, ad2);
  edge_max_kernel<1><<<(E_TOT + 255) / 256, 256, 0, stream>>>(
      src, dst, as2, ad2, menc2);
  edge_p_kernel<1><<<(E_TOT + 255) / 256, 256, 0, stream>>>(
      src, dst, as2, ad2, menc2, p2, denom2);
  aggregate2_kernel<<<N_NODES, 256, 0, stream>>>(yb, p2, denom2, start, deg,
                                                 csr, src, b2, out);
}

// Round 3
// 579.662 us; speedup vs baseline: 1.1314x; 1.0112x over previous
//
#include <hip/hip_runtime.h>
#include <hip/hip_bf16.h>

// ---------------------------------------------------------------------------
// GAT 2-layer model on MI355X — round 3.
// Layer1 commuted: z[n,h,:] = sum_e alpha_{e,h} x[src_e,:]
//                  h2 = ELU(z_h @ W1_h + b1)      (batched MFMA GEMM, BK=64)
// Layer2: y = h2@W2 split-K=4 MFMA (BK=64) -> fused reduce+alpha -> attention.
// Both GEMMs: XCD-locality swizzle so same-A-tile blocks share an XCD L2.
// ---------------------------------------------------------------------------

#define N_NODES 8192
#define N_EDGES 32768
#define E_TOT   (N_EDGES + N_NODES)   // self-loops appended
#define D_IN    768
#define H1      8
#define HC1     (H1 * D_IN)           // 6144
#define KSPLIT  4
#define KSLICE  (HC1 / KSPLIT)        // 1536

typedef unsigned short ushort_t;
using short8  = __attribute__((ext_vector_type(8))) short;
using floatx4 = __attribute__((ext_vector_type(4))) float;

__device__ __forceinline__ float bf2f(unsigned short u) {
  return __uint_as_float(((unsigned)u) << 16);
}
__device__ __forceinline__ unsigned short f2bf(float f) {
  unsigned u = __float_as_uint(f);
  unsigned r = (u + 0x7fffu + ((u >> 16) & 1u)) >> 16;  // RNE
  return (unsigned short)r;
}
// order-preserving float<->uint for atomicMax on floats (incl. negatives)
__device__ __forceinline__ unsigned fenc(float f) {
  unsigned u = __float_as_uint(f);
  return (u & 0x80000000u) ? ~u : (u | 0x80000000u);
}
__device__ __forceinline__ float fdec(unsigned u) {
  return __uint_as_float((u & 0x80000000u) ? (u ^ 0x80000000u) : ~u);
}

__device__ __forceinline__ void async_copy16(void* lds, const void* g) {
  __builtin_amdgcn_global_load_lds(
      (__attribute__((address_space(1))) void*)(g),
      (__attribute__((address_space(3))) void*)(lds), 16, 0, 0);
}

// ---------------------------------------------------------------------------
// fp32 [R][C] -> bf16 transpose [C][R]
// ---------------------------------------------------------------------------
__global__ void transpose_f2b_kernel(const float* __restrict__ in,
                                     ushort_t* __restrict__ out, int R, int C) {
  __shared__ float tile[32][33];
  int bx = blockIdx.x * 32;
  int by = blockIdx.y * 32;
  int tx = threadIdx.x, ty = threadIdx.y;  // (32, 8)
#pragma unroll
  for (int i = 0; i < 32; i += 8)
    tile[ty + i][tx] = in[(size_t)(by + ty + i) * C + bx + tx];
  __syncthreads();
#pragma unroll
  for (int i = 0; i < 32; i += 8)
    out[(size_t)(bx + ty + i) * R + by + tx] = f2bf(tile[tx][ty + i]);
}

// ---------------------------------------------------------------------------
// awS[d][h] = sum_c W1[d][h*768+c]*a_src1[h*768+c]; awD likewise. d=blockIdx.
// ---------------------------------------------------------------------------
__global__ void prep_aw_kernel(const float* __restrict__ W1,
                               const float* __restrict__ aS,
                               const float* __restrict__ aD,
                               float* __restrict__ awS,
                               float* __restrict__ awD) {
  const int d = blockIdx.x;
  const int t = threadIdx.x;
  const float* row = W1 + (size_t)d * HC1;
  float ps[H1], pd[H1];
#pragma unroll
  for (int h = 0; h < H1; ++h) { ps[h] = 0.f; pd[h] = 0.f; }
#pragma unroll
  for (int h = 0; h < H1; ++h)
#pragma unroll
    for (int j = 0; j < 3; ++j) {
      int idx = h * 768 + j * 256 + t;
      float w = row[idx];
      ps[h] += w * aS[idx];
      pd[h] += w * aD[idx];
    }
#pragma unroll
  for (int h = 0; h < H1; ++h)
    for (int off = 32; off > 0; off >>= 1) {
      ps[h] += __shfl_down(ps[h], off, 64);
      pd[h] += __shfl_down(pd[h], off, 64);
    }
  __shared__ float red[2][4][H1];
  int w = t >> 6;
  if ((t & 63) == 0) {
#pragma unroll
    for (int h = 0; h < H1; ++h) { red[0][w][h] = ps[h]; red[1][w][h] = pd[h]; }
  }
  __syncthreads();
  if (t < H1)
    awS[d * H1 + t] = red[0][0][t] + red[0][1][t] + red[0][2][t] + red[0][3][t];
  else if (t >= 64 && t < 64 + H1) {
    int h = t - 64;
    awD[d * H1 + h] = red[1][0][h] + red[1][1][h] + red[1][2][h] + red[1][3][h];
  }
}

// ---------------------------------------------------------------------------
// per node: xb = bf16(x); as1[n,h] = x[n,:]@awS[:,h]; ad1 likewise.
// ---------------------------------------------------------------------------
__global__ void node_prep_kernel(const float* __restrict__ x,
                                 const float* __restrict__ awS,
                                 const float* __restrict__ awD,
                                 ushort_t* __restrict__ xb,
                                 float* __restrict__ as1,
                                 float* __restrict__ ad1) {
  const int n = blockIdx.x;
  const int t = threadIdx.x;
  float ps[H1], pd[H1];
#pragma unroll
  for (int h = 0; h < H1; ++h) { ps[h] = 0.f; pd[h] = 0.f; }
#pragma unroll
  for (int j = 0; j < 3; ++j) {
    int d = j * 256 + t;
    float xv = x[(size_t)n * 768 + d];
    xb[(size_t)n * 768 + d] = f2bf(xv);
    const float4* s4 = (const float4*)(awS + d * 8);
    const float4* d4 = (const float4*)(awD + d * 8);
    float4 a0 = s4[0], a1 = s4[1];
    float4 c0 = d4[0], c1 = d4[1];
    ps[0] += xv * a0.x; ps[1] += xv * a0.y; ps[2] += xv * a0.z; ps[3] += xv * a0.w;
    ps[4] += xv * a1.x; ps[5] += xv * a1.y; ps[6] += xv * a1.z; ps[7] += xv * a1.w;
    pd[0] += xv * c0.x; pd[1] += xv * c0.y; pd[2] += xv * c0.z; pd[3] += xv * c0.w;
    pd[4] += xv * c1.x; pd[5] += xv * c1.y; pd[6] += xv * c1.z; pd[7] += xv * c1.w;
  }
#pragma unroll
  for (int h = 0; h < H1; ++h)
    for (int off = 32; off > 0; off >>= 1) {
      ps[h] += __shfl_down(ps[h], off, 64);
      pd[h] += __shfl_down(pd[h], off, 64);
    }
  __shared__ float red[2][4][H1];
  int w = t >> 6;
  if ((t & 63) == 0) {
#pragma unroll
    for (int h = 0; h < H1; ++h) { red[0][w][h] = ps[h]; red[1][w][h] = pd[h]; }
  }
  __syncthreads();
  if (t < H1)
    as1[n * H1 + t] = red[0][0][t] + red[0][1][t] + red[0][2][t] + red[0][3][t];
  else if (t >= 64 && t < 64 + H1) {
    int h = t - 64;
    ad1[n * H1 + h] = red[1][0][h] + red[1][1][h] + red[1][2][h] + red[1][3][h];
  }
}

// ---------------------------------------------------------------------------
// edge logits -> segment max (ordered-uint atomicMax); then p/denom
// ---------------------------------------------------------------------------
template <int H>
__global__ void edge_max_kernel(const int* __restrict__ src,
                                const int* __restrict__ dst,
                                const float* __restrict__ as_,
                                const float* __restrict__ ad_,
                                unsigned* __restrict__ menc) {
  int gid = blockIdx.x * blockDim.x + threadIdx.x;
  if (gid >= E_TOT * H) return;
  int e = gid / H, h = gid % H;
  int s, d;
  if (e < N_EDGES) { s = src[e]; d = dst[e]; } else { s = d = e - N_EDGES; }
  float l = as_[s * H + h] + ad_[d * H + h];
  l = l > 0.f ? l : 0.2f * l;
  atomicMax(&menc[d * H + h], fenc(l));
}

template <int H>
__global__ void edge_p_kernel(const int* __restrict__ src,
                              const int* __restrict__ dst,
                              const float* __restrict__ as_,
                              const float* __restrict__ ad_,
                              const unsigned* __restrict__ menc,
                              float* __restrict__ p,
                              float* __restrict__ denom) {
  int gid = blockIdx.x * blockDim.x + threadIdx.x;
  if (gid >= E_TOT * H) return;
  int e = gid / H, h = gid % H;
  int s, d;
  if (e < N_EDGES) { s = src[e]; d = dst[e]; } else { s = d = e - N_EDGES; }
  float l = as_[s * H + h] + ad_[d * H + h];
  l = l > 0.f ? l : 0.2f * l;
  float pv = __expf(l - fdec(menc[d * H + h]));
  p[e * H + h] = pv;
  atomicAdd(&denom[d * H + h], pv);
}

// ---------------------------------------------------------------------------
// CSR build: deg -> exclusive scan -> fill
// ---------------------------------------------------------------------------
__global__ void deg_kernel(const int* __restrict__ dst, int* __restrict__ deg) {
  int e = blockIdx.x * blockDim.x + threadIdx.x;
  if (e >= E_TOT) return;
  int d = (e < N_EDGES) ? dst[e] : (e - N_EDGES);
  atomicAdd(&deg[d], 1);
}

__global__ void scan_kernel(const int* __restrict__ deg, int* __restrict__ start,
                            int* __restrict__ cursor) {
  __shared__ int sums[1024];
  int t = threadIdx.x;
  int base = t * 8;
  int local[8];
  int s = 0;
#pragma unroll
  for (int i = 0; i < 8; ++i) { local[i] = s; s += deg[base + i]; }
  sums[t] = s;
  __syncthreads();
  for (int off = 1; off < 1024; off <<= 1) {
    int v = (t >= off) ? sums[t - off] : 0;
    __syncthreads();
    sums[t] += v;
    __syncthreads();
  }
  int excl = (t == 0) ? 0 : sums[t - 1];
#pragma unroll
  for (int i = 0; i < 8; ++i) {
    int st = excl + local[i];
    start[base + i] = st;
    cursor[base + i] = st;
  }
}

__global__ void fill_kernel(const int* __restrict__ dst, int* __restrict__ cursor,
                            int* __restrict__ csr) {
  int e = blockIdx.x * blockDim.x + threadIdx.x;
  if (e >= E_TOT) return;
  int d = (e < N_EDGES) ? dst[e] : (e - N_EDGES);
  int pos = atomicAdd(&cursor[d], 1);
  csr[pos] = e;
}

// ---------------------------------------------------------------------------
// z[n,h,c] = sum_e alpha_{e,h} * xb[src_e, c]  (bf16 out, [N][H][768])
// ---------------------------------------------------------------------------
__global__ __launch_bounds__(256) void aggregate_z_kernel(
    const ushort_t* __restrict__ xb, const float* __restrict__ p1,
    const float* __restrict__ denom1, const int* __restrict__ start,
    const int* __restrict__ deg, const int* __restrict__ csr,
    const int* __restrict__ src, ushort_t* __restrict__ z) {
  const int n = blockIdx.x;
  const int t = threadIdx.x;
  float invd[H1];
#pragma unroll
  for (int h = 0; h < H1; ++h) invd[h] = 1.0f / denom1[n * H1 + h];
  float acc[H1][3];
#pragma unroll
  for (int h = 0; h < H1; ++h)
#pragma unroll
    for (int j = 0; j < 3; ++j) acc[h][j] = 0.f;

  const int st = start[n], dg = deg[n];
  for (int ei = 0; ei < dg; ++ei) {
    int e = csr[st + ei];
    int s = (e < N_EDGES) ? src[e] : (e - N_EDGES);
    float al[H1];
#pragma unroll
    for (int h = 0; h < H1; ++h) al[h] = p1[e * H1 + h] * invd[h];
    float xv[3];
#pragma unroll
    for (int j = 0; j < 3; ++j) xv[j] = bf2f(xb[(size_t)s * 768 + j * 256 + t]);
#pragma unroll
    for (int h = 0; h < H1; ++h)
#pragma unroll
      for (int j = 0; j < 3; ++j) acc[h][j] += al[h] * xv[j];
  }
#pragma unroll
  for (int h = 0; h < H1; ++h)
#pragma unroll
    for (int j = 0; j < 3; ++j)
      z[(size_t)n * HC1 + h * 768 + j * 256 + t] = f2bf(acc[h][j]);
}

// ---------------------------------------------------------------------------
// Shared BK=64 MFMA core. LDS layout per matrix: 8 row-blocks x 2 k-halves
// x 64 fragment slots (short8). 32 KB total LDS -> ~5 blocks/CU.
// ---------------------------------------------------------------------------
#define GEMM_CORE(A_, lda_, Bt_, ldb_, kbeg_, kend_)                           \
  for (int k0 = (kbeg_); k0 < (kend_); k0 += 64) {                             \
    __syncthreads();                                                           \
    _Pragma("unroll") for (int ii = 0; ii < 4; ++ii) {                         \
      int u = w * 4 + ii;                                                      \
      int blk = u >> 1, kk = u & 1;                                            \
      const ushort_t* sa =                                                     \
          (A_) + (size_t)(m0 + blk * 16 + lrow) * (lda_) + k0 + kk * 32 + lq * 8; \
      async_copy16(&Ash[blk * 128 + kk * 64], sa);                             \
      const ushort_t* sb =                                                     \
          (Bt_) + (size_t)(n0 + blk * 16 + lrow) * (ldb_) + k0 + kk * 32 + lq * 8; \
      async_copy16(&Bsh[blk * 128 + kk * 64], sb);                             \
    }                                                                          \
    __syncthreads();                                                           \
    _Pragma("unroll") for (int kk = 0; kk < 2; ++kk) {                         \
      short8 afr[4], bfr[4];                                                   \
      _Pragma("unroll") for (int i = 0; i < 4; ++i)                            \
          afr[i] = Ash[(4 * wm + i) * 128 + kk * 64 + lane];                   \
      _Pragma("unroll") for (int j = 0; j < 4; ++j)                            \
          bfr[j] = Bsh[(4 * wn + j) * 128 + kk * 64 + lane];                   \
      _Pragma("unroll") for (int i = 0; i < 4; ++i)                            \
          _Pragma("unroll") for (int j = 0; j < 4; ++j)                        \
              acc[i][j] = __builtin_amdgcn_mfma_f32_16x16x32_bf16(             \
                  afr[i], bfr[j], acc[i][j], 0, 0, 0);                         \
    }                                                                          \
  }

// ---------------------------------------------------------------------------
// Batched per-head GEMM (layer1): h2b_h = ELU(z_h @ W1_h^T + b1_h), bf16 out.
// Grid: 3072 1-D, XCD swizzle: c=id&7, j=id>>3, n=j%6, mh=(j/6)*8+c,
// head=mh&7, m=mh>>3 -> 6 same-A-tile blocks land on one XCD.
// ---------------------------------------------------------------------------
__global__ __launch_bounds__(256) void gemm_l1_kernel(
    const ushort_t* __restrict__ Ab, const ushort_t* __restrict__ Btb,
    const float* __restrict__ biasb, ushort_t* __restrict__ Cb) {
  __shared__ short8 Ash[1024];
  __shared__ short8 Bsh[1024];
  const int id = blockIdx.x;
  const int c = id & 7;
  const int j = id >> 3;
  const int n = j % 6;
  const int mh = (j / 6) * 8 + c;
  const int head = mh & 7;
  const int m = mh >> 3;
  const ushort_t* A  = Ab + head * 768;                   // lda = HC1
  const ushort_t* Bt = Btb + (size_t)head * 768 * 768;    // ldb = 768
  const float* bias  = biasb + head * 768;
  ushort_t* C        = Cb + head * 768;                   // ldc = HC1
  const int tid = threadIdx.x;
  const int lane = tid & 63;
  const int w = tid >> 6;
  const int wm = w >> 1, wn = w & 1;
  const int m0 = m * 128;
  const int n0 = n * 128;
  const int lrow = lane & 15;
  const int lq = lane >> 4;

  floatx4 acc[4][4];
#pragma unroll
  for (int i = 0; i < 4; ++i)
#pragma unroll
    for (int jj = 0; jj < 4; ++jj) acc[i][jj] = {0.f, 0.f, 0.f, 0.f};

  GEMM_CORE(A, HC1, Bt, 768, 0, 768)

#pragma unroll
  for (int i = 0; i < 4; ++i) {
    int row_b = m0 + wm * 64 + i * 16 + lq * 4;
#pragma unroll
    for (int jj = 0; jj < 4; ++jj) {
      int col = n0 + wn * 64 + jj * 16 + lrow;
      float bv = bias[col];
#pragma unroll
      for (int r = 0; r < 4; ++r) {
        float v = acc[i][jj][r] + bv;
        v = v > 0.f ? v : expm1f(v);  // ELU
        C[(size_t)(row_b + r) * HC1 + col] = f2bf(v);
      }
    }
  }
}

// ---------------------------------------------------------------------------
// Layer-2 GEMM split-K: partial_s = h2b[:, sK:(s+1)K] @ w2t slice, fp32 out.
// Grid: 1536 1-D, XCD swizzle: c=id&7, j=id>>3, n=j%6, ms=(j/6)*8+c,
// s=ms&3, m=ms>>2.
// ---------------------------------------------------------------------------
__global__ __launch_bounds__(256) void gemm_l2_kernel(
    const ushort_t* __restrict__ Ag, const ushort_t* __restrict__ Btg,
    float* __restrict__ Cp) {
  __shared__ short8 Ash[1024];
  __shared__ short8 Bsh[1024];
  const int id = blockIdx.x;
  const int c = id & 7;
  const int j = id >> 3;
  const int n = j % 6;
  const int ms = (j / 6) * 8 + c;
  const int s = ms & 3;
  const int m = ms >> 2;
  const int kbase = s * KSLICE;
  float* C = Cp + (size_t)s * N_NODES * 768;
  const int tid = threadIdx.x;
  const int lane = tid & 63;
  const int w = tid >> 6;
  const int wm = w >> 1, wn = w & 1;
  const int m0 = m * 128;
  const int n0 = n * 128;
  const int lrow = lane & 15;
  const int lq = lane >> 4;

  floatx4 acc[4][4];
#pragma unroll
  for (int i = 0; i < 4; ++i)
#pragma unroll
    for (int jj = 0; jj < 4; ++jj) acc[i][jj] = {0.f, 0.f, 0.f, 0.f};

  GEMM_CORE(Ag, HC1, Btg, HC1, kbase, kbase + KSLICE)

#pragma unroll
  for (int i = 0; i < 4; ++i) {
    int row_b = m0 + wm * 64 + i * 16 + lq * 4;
#pragma unroll
    for (int jj = 0; jj < 4; ++jj) {
      int col = n0 + wn * 64 + jj * 16 + lrow;
#pragma unroll
      for (int r = 0; r < 4; ++r)
        C[(size_t)(row_b + r) * 768 + col] = acc[i][jj][r];
    }
  }
}

// ---------------------------------------------------------------------------
// Fused: yb = bf16(sum of 4 partials); as2/ad2 = y . a_src2/a_dst2 per node.
// ---------------------------------------------------------------------------
__global__ void reduce_alpha2_kernel(const float* __restrict__ parts,
                                     const float* __restrict__ aS,
                                     const float* __restrict__ aD,
                                     ushort_t* __restrict__ yb,
                                     float* __restrict__ as2,
                                     float* __restrict__ ad2) {
  const int n = blockIdx.x;
  const int t = threadIdx.x;
  const size_t S = (size_t)N_NODES * 768;
  float ps = 0.f, pd = 0.f;
#pragma unroll
  for (int j = 0; j < 3; ++j) {
    int cidx = j * 256 + t;
    size_t base = (size_t)n * 768 + cidx;
    float v = parts[base] + parts[base + S] + parts[base + 2 * S] +
              parts[base + 3 * S];
    yb[base] = f2bf(v);
    ps += v * aS[cidx];
    pd += v * aD[cidx];
  }
  for (int off = 32; off > 0; off >>= 1) {
    ps += __shfl_down(ps, off, 64);
    pd += __shfl_down(pd, off, 64);
  }
  __shared__ float red[2][4];
  int w = t >> 6;
  if ((t & 63) == 0) { red[0][w] = ps; red[1][w] = pd; }
  __syncthreads();
  if (t == 0) as2[n] = red[0][0] + red[0][1] + red[0][2] + red[0][3];
  if (t == 64) ad2[n] = red[1][0] + red[1][1] + red[1][2] + red[1][3];
}

// ---------------------------------------------------------------------------
// Layer-2 aggregation (H=1): out[n,c] = sum_e alpha * y[src_e, c] + b2 (fp32)
// ---------------------------------------------------------------------------
__global__ __launch_bounds__(256) void aggregate2_kernel(
    const ushort_t* __restrict__ yb, const float* __restrict__ p2,
    const float* __restrict__ denom2, const int* __restrict__ start,
    const int* __restrict__ deg, const int* __restrict__ csr,
    const int* __restrict__ src, const float* __restrict__ b2,
    float* __restrict__ out) {
  const int n = blockIdx.x;
  const int t = threadIdx.x;
  const float invd = 1.0f / denom2[n];
  float a0 = 0.f, a1 = 0.f, a2 = 0.f;
  const int st = start[n], dg = deg[n];
  for (int ei = 0; ei < dg; ++ei) {
    int e = csr[st + ei];
    int s = (e < N_EDGES) ? src[e] : (e - N_EDGES);
    float alpha = p2[e] * invd;
    const ushort_t* row = yb + (size_t)s * 768;
    a0 += alpha * bf2f(row[t]);
    a1 += alpha * bf2f(row[t + 256]);
    a2 += alpha * bf2f(row[t + 512]);
  }
  out[(size_t)n * 768 + t]       = a0 + b2[t];
  out[(size_t)n * 768 + t + 256] = a1 + b2[t + 256];
  out[(size_t)n * 768 + t + 512] = a2 + b2[t + 512];
}

// ---------------------------------------------------------------------------
extern "C" void kernel_launch(void* const* d_in, const int* in_sizes, int n_in,
                              void* d_out, int out_size, void* d_ws, size_t ws_size,
                              hipStream_t stream) {
  const float* x      = (const float*)d_in[0];
  const int*   ei     = (const int*)d_in[1];
  const float* W1     = (const float*)d_in[2];
  const float* a_src1 = (const float*)d_in[3];
  const float* a_dst1 = (const float*)d_in[4];
  const float* b1     = (const float*)d_in[5];
  const float* W2     = (const float*)d_in[6];
  const float* a_src2 = (const float*)d_in[7];
  const float* a_dst2 = (const float*)d_in[8];
  const float* b2     = (const float*)d_in[9];
  float* out = (float*)d_out;
  const int* src = ei;
  const int* dst = ei + N_EDGES;

  char* ws = (char*)d_ws;
  size_t off = 0;
  auto alloc = [&](size_t bytes) -> void* {
    void* p = ws + off;
    off = (off + bytes + 255) & ~(size_t)255;
    return p;
  };

  // --- zero-init block ---
  char* zero_base = (char*)(ws + off);
  unsigned* menc1 = (unsigned*)alloc(N_NODES * H1 * 4);
  float* denom1   = (float*)alloc(N_NODES * H1 * 4);
  unsigned* menc2 = (unsigned*)alloc(N_NODES * 4);
  float* denom2   = (float*)alloc(N_NODES * 4);
  int* deg        = (int*)alloc(N_NODES * 4);
  size_t zero_bytes = (char*)(ws + off) - zero_base;

  float* awS = (float*)alloc(768 * H1 * 4);
  float* awD = (float*)alloc(768 * H1 * 4);
  float* as1 = (float*)alloc(N_NODES * H1 * 4);
  float* ad1 = (float*)alloc(N_NODES * H1 * 4);
  float* as2 = (float*)alloc(N_NODES * 4);
  float* ad2 = (float*)alloc(N_NODES * 4);
  float* p1  = (float*)alloc((size_t)E_TOT * H1 * 4);
  float* p2  = (float*)alloc((size_t)E_TOT * 4);
  int* start  = (int*)alloc(N_NODES * 4);
  int* cursor = (int*)alloc(N_NODES * 4);
  int* csr    = (int*)alloc(E_TOT * 4);
  ushort_t* xb  = (ushort_t*)alloc((size_t)N_NODES * D_IN * 2);  // -> yb later
  ushort_t* w1t = (ushort_t*)alloc((size_t)HC1 * D_IN * 2);
  ushort_t* w2t = (ushort_t*)alloc((size_t)HC1 * D_IN * 2);
  ushort_t* z   = (ushort_t*)alloc((size_t)N_NODES * HC1 * 2);   // -> partials
  ushort_t* h2b = (ushort_t*)alloc((size_t)N_NODES * HC1 * 2);
  ushort_t* yb  = xb;          // xb dead after aggregate_z
  float* parts  = (float*)z;   // z dead after gemm_l1 (same byte size)
  (void)ws_size; (void)n_in; (void)in_sizes; (void)out_size;

  hipMemsetAsync(zero_base, 0, zero_bytes, stream);

  // weight prep
  prep_aw_kernel<<<768, 256, 0, stream>>>(W1, a_src1, a_dst1, awS, awD);
  node_prep_kernel<<<N_NODES, 256, 0, stream>>>(x, awS, awD, xb, as1, ad1);
  transpose_f2b_kernel<<<dim3(HC1 / 32, D_IN / 32), dim3(32, 8), 0, stream>>>(
      W1, w1t, D_IN, HC1);  // [6144][768]
  transpose_f2b_kernel<<<dim3(D_IN / 32, HC1 / 32), dim3(32, 8), 0, stream>>>(
      W2, w2t, HC1, D_IN);  // [768][6144]

  // CSR build (graph identical for both layers)
  deg_kernel<<<(E_TOT + 255) / 256, 256, 0, stream>>>(dst, deg);
  scan_kernel<<<1, 1024, 0, stream>>>(deg, start, cursor);
  fill_kernel<<<(E_TOT + 255) / 256, 256, 0, stream>>>(dst, cursor, csr);

  // layer-1 attention on x-derived logits
  edge_max_kernel<H1><<<(E_TOT * H1 + 255) / 256, 256, 0, stream>>>(
      src, dst, as1, ad1, menc1);
  edge_p_kernel<H1><<<(E_TOT * H1 + 255) / 256, 256, 0, stream>>>(
      src, dst, as1, ad1, menc1, p1, denom1);
  aggregate_z_kernel<<<N_NODES, 256, 0, stream>>>(xb, p1, denom1, start, deg,
                                                  csr, src, z);
  // batched per-head GEMM with fused bias+ELU (XCD-swizzled 1-D grid)
  gemm_l1_kernel<<<6 * 64 * H1, 256, 0, stream>>>(z, w1t, b1, h2b);

  // layer-2 GEMM split-K=4 (XCD-swizzled) + fused reduce+alpha
  gemm_l2_kernel<<<6 * 64 * KSPLIT, 256, 0, stream>>>(h2b, w2t, parts);
  reduce_alpha2_kernel<<<N_NODES, 256, 0, stream>>>(parts, a_src2, a_dst2, yb,
                                                    as2, ad2);

  // layer-2 attention
  edge_max_kernel<1><<<(E_TOT + 255) / 256, 256, 0, stream>>>(
      src, dst, as2, ad2, menc2);
  edge_p_kernel<1><<<(E_TOT + 255) / 256, 256, 0, stream>>>(
      src, dst, as2, ad2, menc2, p2, denom2);
  aggregate2_kernel<<<N_NODES, 256, 0, stream>>>(yb, p2, denom2, start, deg,
                                                 csr, src, b2, out);
}